// Round 2
// baseline (453.911 us; speedup 1.0000x reference)
//
#include <hip/hip_runtime.h>
#include <stdint.h>

#define NODES 100000
#define EDGES 1000000
#define HF 256

// R (node features after W1) layout: [node][512] bf16, cols 0..255 = h@W1b ("P"),
// cols 256..511 = h@W1c ("Q").
// ws layout: [0, 256KB) = packed bf16 W1 fragments; [256KB, +102.4MB) = R.
// ASSUMES ws_size >= 102.7 MB (if this fails, next round adds chunked fallback).

typedef short short8 __attribute__((ext_vector_type(8)));
typedef float f32x4 __attribute__((ext_vector_type(4)));

__device__ __forceinline__ unsigned short f2b(float f) {
  union { float f; uint32_t u; } v; v.f = f;
  return (unsigned short)((v.u + 0x7FFFu + ((v.u >> 16) & 1u)) >> 16);  // RNE
}
__device__ __forceinline__ float b2f(unsigned short s) {
  union { uint32_t u; float f; } v; v.u = ((uint32_t)s) << 16;
  return v.f;
}

// ---------------- pack W1 rows 7..518 into MFMA B-fragment order (bf16) -------------
// Bp[((kb*32+nbg)*64+lane)*8 + j] = Wcat[kb*32+(lane>>4)*8+j][nbg*16+(lane&15)]
// Wcat[k][n] = W1[(n<256 ? 7+k : 263+k)][n&255]   (k in [0,256), n in [0,512))
__global__ __launch_bounds__(256) void pack_w1(const float* __restrict__ W1,
                                               unsigned short* __restrict__ Bp) {
  int idx = blockIdx.x * 256 + threadIdx.x;  // 0..16383
  int lane = idx & 63;
  int nbg  = (idx >> 6) & 31;
  int kb   = idx >> 11;
  int n    = nbg * 16 + (lane & 15);
  int k0   = kb * 32 + (lane >> 4) * 8;
  int rbase = (n < 256) ? 7 : 263;
  int col   = n & 255;
  short8 o;
#pragma unroll
  for (int j = 0; j < 8; ++j)
    o[j] = (short)f2b(W1[(size_t)(rbase + k0 + j) * HF + col]);
  *reinterpret_cast<short8*>(Bp + (size_t)idx * 8) = o;
}

// ---------------- R = h @ Wcat  (M=100000, K=256, N=512), bf16 MFMA ------------------
// grid (1563, 2); block 256 = 4 waves; per block: 64 rows x 256 cols (per y-half).
__global__ __launch_bounds__(256) void gemm_R(const float* __restrict__ h,
                                              const unsigned short* __restrict__ Bp,
                                              unsigned short* __restrict__ R) {
  // stride 264 bf16 = 528 B -> rows advance 1 16B-slot: conflict-free frag reads
  __shared__ unsigned short A[64][264];
  const int m0 = blockIdx.x * 64;
  const int t  = threadIdx.x;
  {
    const int r = t >> 2, q = t & 3;
    const int grow = m0 + r;
    const bool valid = grow < NODES;
    const float* hp = h + (size_t)grow * HF + q * 64;
#pragma unroll
    for (int cc = 0; cc < 8; ++cc) {
      float4 a, b;
      if (valid) {
        a = *reinterpret_cast<const float4*>(hp + cc * 8);
        b = *reinterpret_cast<const float4*>(hp + cc * 8 + 4);
      } else {
        a = make_float4(0.f, 0.f, 0.f, 0.f);
        b = a;
      }
      short8 o;
      o[0]=(short)f2b(a.x); o[1]=(short)f2b(a.y); o[2]=(short)f2b(a.z); o[3]=(short)f2b(a.w);
      o[4]=(short)f2b(b.x); o[5]=(short)f2b(b.y); o[6]=(short)f2b(b.z); o[7]=(short)f2b(b.w);
      *reinterpret_cast<short8*>(&A[r][q * 64 + cc * 8]) = o;
    }
  }
  __syncthreads();

  const int wave = t >> 6, lane = t & 63;
  const int l15 = lane & 15, lhi = lane >> 4;
  const int nbg0 = blockIdx.y * 16 + wave * 4;  // 16-col-group base (global over 512)
  f32x4 acc[4][4] = {};
#pragma unroll
  for (int kb = 0; kb < 8; ++kb) {
    short8 bfrag[4];
#pragma unroll
    for (int nb = 0; nb < 4; ++nb)
      bfrag[nb] = *reinterpret_cast<const short8*>(
          Bp + (((size_t)(kb * 32 + nbg0 + nb) * 64 + lane) * 8));
    short8 afrag[4];
#pragma unroll
    for (int mb = 0; mb < 4; ++mb)
      afrag[mb] = *reinterpret_cast<const short8*>(&A[mb * 16 + l15][kb * 32 + lhi * 8]);
#pragma unroll
    for (int mb = 0; mb < 4; ++mb)
#pragma unroll
      for (int nb = 0; nb < 4; ++nb)
        acc[mb][nb] = __builtin_amdgcn_mfma_f32_16x16x32_bf16(
            afrag[mb], bfrag[nb], acc[mb][nb], 0, 0, 0);
  }
  // C/D layout (m89-verified): col = lane&15, row = (lane>>4)*4 + reg
  const int c0 = blockIdx.y * 256 + wave * 64 + l15;
#pragma unroll
  for (int mb = 0; mb < 4; ++mb) {
#pragma unroll
    for (int i = 0; i < 4; ++i) {
      const int row = m0 + mb * 16 + lhi * 4 + i;
      if (row < NODES) {
        unsigned short* rp = R + (size_t)row * 512 + c0;
#pragma unroll
        for (int nb = 0; nb < 4; ++nb) rp[nb * 16] = f2b(acc[mb][nb][i]);
      }
    }
  }
}

// ---------------- per-edge: out = relu(P[src]+Q[dst]+ef@W1a+b1) @ W2 + b2 ------------
// one wave per edge; lane owns hid cols [4*lane, 4*lane+4)
__global__ __launch_bounds__(256) void edge_mlp(
    const unsigned short* __restrict__ R, const float* __restrict__ ef,
    const int* __restrict__ src, const int* __restrict__ dst,
    const float* __restrict__ W1, const float* __restrict__ b1,
    const float* __restrict__ W2, const float* __restrict__ b2,
    float* __restrict__ out) {
  const int lane = threadIdx.x & 63;
  const int wid  = (blockIdx.x * blockDim.x + threadIdx.x) >> 6;
  const int nw   = (gridDim.x * blockDim.x) >> 6;

  // persistent per-lane weights (reused across all edges this wave handles)
  float w1a[7][4];
#pragma unroll
  for (int j = 0; j < 7; ++j) {
    float4 v = *reinterpret_cast<const float4*>(W1 + (size_t)j * HF + lane * 4);
    w1a[j][0] = v.x; w1a[j][1] = v.y; w1a[j][2] = v.z; w1a[j][3] = v.w;
  }
  float w2r[4][4];
#pragma unroll
  for (int i = 0; i < 4; ++i) {
    float4 v = *reinterpret_cast<const float4*>(W2 + (size_t)(lane * 4 + i) * 4);
    w2r[i][0] = v.x; w2r[i][1] = v.y; w2r[i][2] = v.z; w2r[i][3] = v.w;
  }
  const float4 b1v = *reinterpret_cast<const float4*>(b1 + lane * 4);
  const float4 b2v = *reinterpret_cast<const float4*>(b2);

  for (int e = wid; e < EDGES; e += nw) {
    const int es = __builtin_amdgcn_readfirstlane(e);
    const int s = src[es];
    const int d = dst[es];
    const ushort4 pv = *reinterpret_cast<const ushort4*>(R + (size_t)s * 512 + lane * 4);
    const ushort4 qv = *reinterpret_cast<const ushort4*>(R + (size_t)d * 512 + 256 + lane * 4);
    float efv[7];
#pragma unroll
    for (int j = 0; j < 7; ++j) efv[j] = ef[(size_t)es * 7 + j];

    float h0 = b2f(pv.x) + b2f(qv.x) + b1v.x;
    float h1 = b2f(pv.y) + b2f(qv.y) + b1v.y;
    float h2 = b2f(pv.z) + b2f(qv.z) + b1v.z;
    float h3 = b2f(pv.w) + b2f(qv.w) + b1v.w;
#pragma unroll
    for (int j = 0; j < 7; ++j) {
      h0 = fmaf(efv[j], w1a[j][0], h0);
      h1 = fmaf(efv[j], w1a[j][1], h1);
      h2 = fmaf(efv[j], w1a[j][2], h2);
      h3 = fmaf(efv[j], w1a[j][3], h3);
    }
    h0 = fmaxf(h0, 0.f); h1 = fmaxf(h1, 0.f);
    h2 = fmaxf(h2, 0.f); h3 = fmaxf(h3, 0.f);

    float a0 = h0 * w2r[0][0]; a0 = fmaf(h1, w2r[1][0], a0); a0 = fmaf(h2, w2r[2][0], a0); a0 = fmaf(h3, w2r[3][0], a0);
    float a1 = h0 * w2r[0][1]; a1 = fmaf(h1, w2r[1][1], a1); a1 = fmaf(h2, w2r[2][1], a1); a1 = fmaf(h3, w2r[3][1], a1);
    float a2 = h0 * w2r[0][2]; a2 = fmaf(h1, w2r[1][2], a2); a2 = fmaf(h2, w2r[2][2], a2); a2 = fmaf(h3, w2r[3][2], a2);
    float a3 = h0 * w2r[0][3]; a3 = fmaf(h1, w2r[1][3], a3); a3 = fmaf(h2, w2r[2][3], a3); a3 = fmaf(h3, w2r[3][3], a3);

#pragma unroll
    for (int off = 32; off > 0; off >>= 1) {
      a0 += __shfl_xor(a0, off);
      a1 += __shfl_xor(a1, off);
      a2 += __shfl_xor(a2, off);
      a3 += __shfl_xor(a3, off);
    }
    if (lane == 0) {
      float4 o;
      o.x = a0 + b2v.x; o.y = a1 + b2v.y; o.z = a2 + b2v.z; o.w = a3 + b2v.w;
      *reinterpret_cast<float4*>(out + (size_t)e * 4) = o;
    }
  }
}

extern "C" void kernel_launch(void* const* d_in, const int* in_sizes, int n_in,
                              void* d_out, int out_size, void* d_ws, size_t ws_size,
                              hipStream_t stream) {
  const float* h  = (const float*)d_in[0];
  const float* ef = (const float*)d_in[1];
  const int* src  = (const int*)d_in[2];
  const int* dst  = (const int*)d_in[3];
  const float* W1 = (const float*)d_in[4];
  const float* b1 = (const float*)d_in[5];
  const float* W2 = (const float*)d_in[6];
  const float* b2 = (const float*)d_in[7];
  float* out = (float*)d_out;

  const size_t bp_bytes = (size_t)8 * 32 * 64 * 8 * 2;          // 262144
  unsigned short* Bp = (unsigned short*)d_ws;
  unsigned short* R  = (unsigned short*)((char*)d_ws + bp_bytes);
  // needs bp_bytes + NODES*512*2 = ~102.7 MB of ws; gambling ws_size suffices.

  pack_w1<<<64, 256, 0, stream>>>(W1, Bp);
  gemm_R<<<dim3((NODES + 63) / 64, 2), 256, 0, stream>>>(h, Bp, R);
  edge_mlp<<<2048, 256, 0, stream>>>(R, ef, src, dst, W1, b1, W2, b2, out);
}

// Round 3
// 248.083 us; speedup vs baseline: 1.8297x; 1.8297x over previous
//
#include <hip/hip_runtime.h>
#include <stdint.h>

#define NODES 100000
#define EDGES 1000000
#define HF 256
#define TILES (EDGES / 16)

// ws layout: [0, 256KB) = packed bf16 W1 B-fragments; [256KB, +102.4MB) = R.
// R[node][512] bf16: cols 0..255 = h@W1[7:263] + b1 ("P"), cols 256..511 = h@W1[263:519] ("Q").

typedef short short8 __attribute__((ext_vector_type(8)));
typedef float f32x4 __attribute__((ext_vector_type(4)));
typedef int i32x4 __attribute__((ext_vector_type(4)));

__device__ __forceinline__ unsigned short f2b(float f) {
  union { float f; uint32_t u; } v; v.f = f;
  return (unsigned short)((v.u + 0x7FFFu + ((v.u >> 16) & 1u)) >> 16);  // RNE
}
__device__ __forceinline__ float b2f(unsigned short s) {
  union { uint32_t u; float f; } v; v.u = ((uint32_t)s) << 16;
  return v.f;
}

// ---------------- pack W1 rows 7..518 into MFMA B-fragment order (bf16) -------------
__global__ __launch_bounds__(256) void pack_w1(const float* __restrict__ W1,
                                               unsigned short* __restrict__ Bp) {
  int idx = blockIdx.x * 256 + threadIdx.x;  // 0..16383
  int lane = idx & 63;
  int nbg  = (idx >> 6) & 31;
  int kb   = idx >> 11;
  int n    = nbg * 16 + (lane & 15);
  int k0   = kb * 32 + (lane >> 4) * 8;
  int rbase = (n < 256) ? 7 : 263;
  int col   = n & 255;
  short8 o;
#pragma unroll
  for (int j = 0; j < 8; ++j)
    o[j] = (short)f2b(W1[(size_t)(rbase + k0 + j) * HF + col]);
  *reinterpret_cast<short8*>(Bp + (size_t)idx * 8) = o;
}

// ---------------- R = h @ Wcat (+b1 on P half)  (M=100000, K=256, N=512) -------------
__global__ __launch_bounds__(256) void gemm_R(const float* __restrict__ h,
                                              const unsigned short* __restrict__ Bp,
                                              const float* __restrict__ b1,
                                              unsigned short* __restrict__ R) {
  __shared__ unsigned short A[64][264];
  const int m0 = blockIdx.x * 64;
  const int t  = threadIdx.x;
  {
    const int r = t >> 2, q = t & 3;
    const int grow = m0 + r;
    const bool valid = grow < NODES;
    const float* hp = h + (size_t)grow * HF + q * 64;
#pragma unroll
    for (int cc = 0; cc < 8; ++cc) {
      float4 a, b;
      if (valid) {
        a = *reinterpret_cast<const float4*>(hp + cc * 8);
        b = *reinterpret_cast<const float4*>(hp + cc * 8 + 4);
      } else {
        a = make_float4(0.f, 0.f, 0.f, 0.f);
        b = a;
      }
      short8 o;
      o[0]=(short)f2b(a.x); o[1]=(short)f2b(a.y); o[2]=(short)f2b(a.z); o[3]=(short)f2b(a.w);
      o[4]=(short)f2b(b.x); o[5]=(short)f2b(b.y); o[6]=(short)f2b(b.z); o[7]=(short)f2b(b.w);
      *reinterpret_cast<short8*>(&A[r][q * 64 + cc * 8]) = o;
    }
  }
  __syncthreads();

  const int wave = t >> 6, lane = t & 63;
  const int l15 = lane & 15, lhi = lane >> 4;
  const int nbg0 = blockIdx.y * 16 + wave * 4;
  f32x4 acc[4][4] = {};
#pragma unroll
  for (int kb = 0; kb < 8; ++kb) {
    short8 bfrag[4];
#pragma unroll
    for (int nb = 0; nb < 4; ++nb)
      bfrag[nb] = *reinterpret_cast<const short8*>(
          Bp + (((size_t)(kb * 32 + nbg0 + nb) * 64 + lane) * 8));
    short8 afrag[4];
#pragma unroll
    for (int mb = 0; mb < 4; ++mb)
      afrag[mb] = *reinterpret_cast<const short8*>(&A[mb * 16 + l15][kb * 32 + lhi * 8]);
#pragma unroll
    for (int mb = 0; mb < 4; ++mb)
#pragma unroll
      for (int nb = 0; nb < 4; ++nb)
        acc[mb][nb] = __builtin_amdgcn_mfma_f32_16x16x32_bf16(
            afrag[mb], bfrag[nb], acc[mb][nb], 0, 0, 0);
  }
  const int c0 = blockIdx.y * 256 + wave * 64 + l15;
  float b1v[4] = {0.f, 0.f, 0.f, 0.f};
  if (blockIdx.y == 0) {  // P half gets b1 folded in
#pragma unroll
    for (int nb = 0; nb < 4; ++nb) b1v[nb] = b1[c0 + nb * 16];
  }
#pragma unroll
  for (int mb = 0; mb < 4; ++mb) {
#pragma unroll
    for (int i = 0; i < 4; ++i) {
      const int row = m0 + mb * 16 + lhi * 4 + i;
      if (row < NODES) {
        unsigned short* rp = R + (size_t)row * 512 + c0;
#pragma unroll
        for (int nb = 0; nb < 4; ++nb) rp[nb * 16] = f2b(acc[mb][nb][i] + b1v[nb]);
      }
    }
  }
}

// ---------------- per-edge MLP, 16 edges per wave via MFMA ---------------------------
// hid[e][k] = relu(P[src_e][k] + Q[dst_e][k] + ef[e]·W1a[:,k])   (b1 already in P)
// out[e][:] = hid[e][:] @ W2 + b2   via mfma_f32_16x16x32_bf16, N=16 (cols 4..15 = 0)
__global__ __launch_bounds__(256) void edge_mlp(
    const unsigned short* __restrict__ R, const float* __restrict__ ef,
    const int* __restrict__ src, const int* __restrict__ dst,
    const float* __restrict__ W1, const float* __restrict__ W2,
    const float* __restrict__ b2, float* __restrict__ out) {
  __shared__ float w1a[7 * 256];
  for (int i = threadIdx.x; i < 7 * 64; i += 256)
    reinterpret_cast<float4*>(w1a)[i] = reinterpret_cast<const float4*>(W1)[i];
  __syncthreads();

  const int lane = threadIdx.x & 63;
  const int l15 = lane & 15, lhi = lane >> 4;

  // B fragment: W2 zero-padded to [256][16], bf16. lane holds B[kb*32+lhi*8+j][l15]
  short8 bfrag[8];
#pragma unroll
  for (int kb = 0; kb < 8; ++kb) {
    short8 b = {0, 0, 0, 0, 0, 0, 0, 0};
    if (l15 < 4) {
#pragma unroll
      for (int j = 0; j < 8; ++j)
        b[j] = (short)f2b(W2[(size_t)(kb * 32 + lhi * 8 + j) * 4 + l15]);
    }
    bfrag[kb] = b;
  }
  const float b2l = (l15 < 4) ? b2[l15] : 0.f;

  const int wid = (blockIdx.x * blockDim.x + threadIdx.x) >> 6;
  const int nw  = (gridDim.x * blockDim.x) >> 6;

  for (int t = wid; t < TILES; t += nw) {
    const int e0 = t * 16;
    const int ei = e0 + l15;
    const int s = src[ei];
    const int d = dst[ei];
    float efv[7];
#pragma unroll
    for (int j = 0; j < 7; ++j) efv[j] = ef[(size_t)ei * 7 + j];

    const unsigned short* Pp = R + (size_t)s * 512 + lhi * 8;
    const unsigned short* Qp = R + (size_t)d * 512 + 256 + lhi * 8;
    f32x4 acc = {};
#pragma unroll
    for (int kb = 0; kb < 8; ++kb) {
      const short8 pv = *reinterpret_cast<const short8*>(Pp + kb * 32);
      const short8 qv = *reinterpret_cast<const short8*>(Qp + kb * 32);
      float hd[8];
#pragma unroll
      for (int j2 = 0; j2 < 8; ++j2)
        hd[j2] = b2f((unsigned short)pv[j2]) + b2f((unsigned short)qv[j2]);
      const float* ws = w1a + kb * 32 + lhi * 8;
#pragma unroll
      for (int j = 0; j < 7; ++j) {
        const float4 wa = *reinterpret_cast<const float4*>(ws + j * 256);
        const float4 wb = *reinterpret_cast<const float4*>(ws + j * 256 + 4);
        hd[0] = fmaf(efv[j], wa.x, hd[0]);
        hd[1] = fmaf(efv[j], wa.y, hd[1]);
        hd[2] = fmaf(efv[j], wa.z, hd[2]);
        hd[3] = fmaf(efv[j], wa.w, hd[3]);
        hd[4] = fmaf(efv[j], wb.x, hd[4]);
        hd[5] = fmaf(efv[j], wb.y, hd[5]);
        hd[6] = fmaf(efv[j], wb.z, hd[6]);
        hd[7] = fmaf(efv[j], wb.w, hd[7]);
      }
      union { i32x4 i; short8 s8; } af;
#pragma unroll
      for (int w = 0; w < 4; ++w) {
        const float lo = fmaxf(hd[2 * w], 0.f);
        const float hi = fmaxf(hd[2 * w + 1], 0.f);
        uint32_t pk;
        asm("v_cvt_pk_bf16_f32 %0, %1, %2" : "=v"(pk) : "v"(lo), "v"(hi));
        af.i[w] = (int)pk;
      }
      acc = __builtin_amdgcn_mfma_f32_16x16x32_bf16(af.s8, bfrag[kb], acc, 0, 0, 0);
    }
    // C layout: col = lane&15 (= output n), row = (lane>>4)*4 + i (= edge in tile)
    if (l15 < 4) {
#pragma unroll
      for (int i = 0; i < 4; ++i)
        out[(size_t)(e0 + lhi * 4 + i) * 4 + l15] = acc[i] + b2l;
    }
  }
}

extern "C" void kernel_launch(void* const* d_in, const int* in_sizes, int n_in,
                              void* d_out, int out_size, void* d_ws, size_t ws_size,
                              hipStream_t stream) {
  const float* h  = (const float*)d_in[0];
  const float* ef = (const float*)d_in[1];
  const int* src  = (const int*)d_in[2];
  const int* dst  = (const int*)d_in[3];
  const float* W1 = (const float*)d_in[4];
  const float* b1 = (const float*)d_in[5];
  const float* W2 = (const float*)d_in[6];
  const float* b2 = (const float*)d_in[7];
  float* out = (float*)d_out;

  const size_t bp_bytes = (size_t)8 * 32 * 64 * 8 * 2;  // 262144
  unsigned short* Bp = (unsigned short*)d_ws;
  unsigned short* R  = (unsigned short*)((char*)d_ws + bp_bytes);

  pack_w1<<<64, 256, 0, stream>>>(W1, Bp);
  gemm_R<<<dim3((NODES + 63) / 64, 2), 256, 0, stream>>>(h, Bp, b1, R);
  edge_mlp<<<2048, 256, 0, stream>>>(R, ef, src, dst, W1, W2, b2, out);
}

// Round 4
// 239.896 us; speedup vs baseline: 1.8921x; 1.0341x over previous
//
#include <hip/hip_runtime.h>
#include <stdint.h>

#define NODES 100000
#define EDGES 1000000
#define HF 256
#define TILES2 (EDGES / 32)

// ws layout: [0, 256KB) = packed bf16 W1 B-fragments; [256KB, +102.4MB) = R.
// R[node][512] bf16: cols 0..255 = h@W1[7:263] + b1 ("P"), cols 256..511 = h@W1[263:519] ("Q").

typedef short short8 __attribute__((ext_vector_type(8)));
typedef float f32x4 __attribute__((ext_vector_type(4)));
typedef float f32x2 __attribute__((ext_vector_type(2)));
typedef int i32x4 __attribute__((ext_vector_type(4)));

__device__ __forceinline__ unsigned short f2b(float f) {
  union { float f; uint32_t u; } v; v.f = f;
  return (unsigned short)((v.u + 0x7FFFu + ((v.u >> 16) & 1u)) >> 16);  // RNE
}
__device__ __forceinline__ float asf(uint32_t u) {
  union { uint32_t u; float f; } v; v.u = u;
  return v.f;
}
__device__ __forceinline__ uint32_t cvtpk(float lo, float hi) {
  uint32_t pk;
  asm("v_cvt_pk_bf16_f32 %0, %1, %2" : "=v"(pk) : "v"(lo), "v"(hi));
  return pk;
}

// ---------------- pack W1 rows 7..518 into MFMA B-fragment order (bf16) -------------
__global__ __launch_bounds__(256) void pack_w1(const float* __restrict__ W1,
                                               unsigned short* __restrict__ Bp) {
  int idx = blockIdx.x * 256 + threadIdx.x;  // 0..16383
  int lane = idx & 63;
  int nbg  = (idx >> 6) & 31;
  int kb   = idx >> 11;
  int n    = nbg * 16 + (lane & 15);
  int k0   = kb * 32 + (lane >> 4) * 8;
  int rbase = (n < 256) ? 7 : 263;
  int col   = n & 255;
  short8 o;
#pragma unroll
  for (int j = 0; j < 8; ++j)
    o[j] = (short)f2b(W1[(size_t)(rbase + k0 + j) * HF + col]);
  *reinterpret_cast<short8*>(Bp + (size_t)idx * 8) = o;
}

// ---------------- R = h @ Wcat (+b1 on P half)  (M=100000, K=256, N=512) -------------
__global__ __launch_bounds__(256) void gemm_R(const float* __restrict__ h,
                                              const unsigned short* __restrict__ Bp,
                                              const float* __restrict__ b1,
                                              unsigned short* __restrict__ R) {
  __shared__ unsigned short A[64][264];
  const int m0 = blockIdx.x * 64;
  const int t  = threadIdx.x;
  {
    const int r = t >> 2, q = t & 3;
    const int grow = m0 + r;
    const bool valid = grow < NODES;
    const float* hp = h + (size_t)grow * HF + q * 64;
#pragma unroll
    for (int cc = 0; cc < 8; ++cc) {
      float4 a, b;
      if (valid) {
        a = *reinterpret_cast<const float4*>(hp + cc * 8);
        b = *reinterpret_cast<const float4*>(hp + cc * 8 + 4);
      } else {
        a = make_float4(0.f, 0.f, 0.f, 0.f);
        b = a;
      }
      uint32_t o32[4];
      o32[0] = cvtpk(a.x, a.y);
      o32[1] = cvtpk(a.z, a.w);
      o32[2] = cvtpk(b.x, b.y);
      o32[3] = cvtpk(b.z, b.w);
      *reinterpret_cast<uint4*>(&A[r][q * 64 + cc * 8]) =
          make_uint4(o32[0], o32[1], o32[2], o32[3]);
    }
  }
  __syncthreads();

  const int wave = t >> 6, lane = t & 63;
  const int l15 = lane & 15, lhi = lane >> 4;
  const int nbg0 = blockIdx.y * 16 + wave * 4;
  f32x4 acc[4][4] = {};
#pragma unroll
  for (int kb = 0; kb < 8; ++kb) {
    short8 bfrag[4];
#pragma unroll
    for (int nb = 0; nb < 4; ++nb)
      bfrag[nb] = *reinterpret_cast<const short8*>(
          Bp + (((size_t)(kb * 32 + nbg0 + nb) * 64 + lane) * 8));
    short8 afrag[4];
#pragma unroll
    for (int mb = 0; mb < 4; ++mb)
      afrag[mb] = *reinterpret_cast<const short8*>(&A[mb * 16 + l15][kb * 32 + lhi * 8]);
#pragma unroll
    for (int mb = 0; mb < 4; ++mb)
#pragma unroll
      for (int nb = 0; nb < 4; ++nb)
        acc[mb][nb] = __builtin_amdgcn_mfma_f32_16x16x32_bf16(
            afrag[mb], bfrag[nb], acc[mb][nb], 0, 0, 0);
  }
  const int c0 = blockIdx.y * 256 + wave * 64 + l15;
  float b1v[4] = {0.f, 0.f, 0.f, 0.f};
  if (blockIdx.y == 0) {  // P half gets b1 folded in
#pragma unroll
    for (int nb = 0; nb < 4; ++nb) b1v[nb] = b1[c0 + nb * 16];
  }
#pragma unroll
  for (int mb = 0; mb < 4; ++mb) {
#pragma unroll
    for (int i = 0; i < 4; ++i) {
      const int row = m0 + mb * 16 + lhi * 4 + i;
      if (row < NODES) {
        unsigned short* rp = R + (size_t)row * 512 + c0;
#pragma unroll
        for (int nb = 0; nb < 4; ++nb) rp[nb * 16] = f2b(acc[mb][nb][i] + b1v[nb]);
      }
    }
  }
}

// ---------------- per-edge MLP, 32 edges (2 MFMA tiles) per wave iteration -----------
// hid[e][k] = relu(P[src_e][k] + Q[dst_e][k] + ef[e]·W1a[:,k])   (b1 already in P)
// out[e][:] = hid[e][:] @ W2 + b2   via mfma_f32_16x16x32_bf16, N=16 (cols 4..15 = 0)
__global__ __launch_bounds__(256) void edge_mlp(
    const unsigned short* __restrict__ R, const float* __restrict__ ef,
    const int* __restrict__ src, const int* __restrict__ dst,
    const float* __restrict__ W1, const float* __restrict__ W2,
    const float* __restrict__ b2, float* __restrict__ out) {
  __shared__ float w1a[7 * 256];
  for (int i = threadIdx.x; i < 7 * 64; i += 256)
    reinterpret_cast<float4*>(w1a)[i] = reinterpret_cast<const float4*>(W1)[i];
  __syncthreads();

  const int lane = threadIdx.x & 63;
  const int l15 = lane & 15, lhi = lane >> 4;

  // B fragment: W2 zero-padded to [256][16], bf16. lane holds B[kb*32+lhi*8+j][l15]
  short8 bfrag[8];
#pragma unroll
  for (int kb = 0; kb < 8; ++kb) {
    short8 b = {0, 0, 0, 0, 0, 0, 0, 0};
    if (l15 < 4) {
#pragma unroll
      for (int j = 0; j < 8; ++j)
        b[j] = (short)f2b(W2[(size_t)(kb * 32 + lhi * 8 + j) * 4 + l15]);
    }
    bfrag[kb] = b;
  }
  const float b2l = (l15 < 4) ? b2[l15] : 0.f;

  const int wid = (blockIdx.x * blockDim.x + threadIdx.x) >> 6;
  const int nw  = (gridDim.x * blockDim.x) >> 6;

// Per-tile per-kb compute: unpack P/Q bf16 pairs, packed-f32 ef FMA, relu, pack, MFMA.
#define TILE_KB(PV, QV, EFV, ACC)                                              \
  {                                                                            \
    const uint32_t* pu = reinterpret_cast<const uint32_t*>(&PV);               \
    const uint32_t* qu = reinterpret_cast<const uint32_t*>(&QV);               \
    f32x2 hd[4];                                                               \
    _Pragma("unroll") for (int w = 0; w < 4; ++w) {                            \
      f32x2 p2 = {asf(pu[w] << 16), asf(pu[w] & 0xffff0000u)};                 \
      f32x2 q2 = {asf(qu[w] << 16), asf(qu[w] & 0xffff0000u)};                 \
      hd[w] = p2 + q2;                                                         \
    }                                                                          \
    _Pragma("unroll") for (int j = 0; j < 7; ++j) {                            \
      f32x2 e2 = {EFV[j], EFV[j]};                                             \
      hd[0] = wv[j][0] * e2 + hd[0];                                           \
      hd[1] = wv[j][1] * e2 + hd[1];                                           \
      hd[2] = wv[j][2] * e2 + hd[2];                                           \
      hd[3] = wv[j][3] * e2 + hd[3];                                           \
    }                                                                          \
    union { i32x4 i; short8 s8; } af;                                          \
    _Pragma("unroll") for (int w = 0; w < 4; ++w) {                            \
      const float lo = fmaxf(hd[w][0], 0.f);                                   \
      const float hi = fmaxf(hd[w][1], 0.f);                                   \
      af.i[w] = (int)cvtpk(lo, hi);                                            \
    }                                                                          \
    ACC = __builtin_amdgcn_mfma_f32_16x16x32_bf16(af.s8, bfrag[kb], ACC, 0, 0, 0); \
  }

  for (int t = wid; t < TILES2; t += nw) {
    const int e0 = t * 32;
    const int eiA = e0 + l15;
    const int eiB = eiA + 16;
    const int sA = src[eiA], dA = dst[eiA];
    const int sB = src[eiB], dB = dst[eiB];
    float efA[7], efB[7];
#pragma unroll
    for (int j = 0; j < 7; ++j) {
      efA[j] = ef[(size_t)eiA * 7 + j];
      efB[j] = ef[(size_t)eiB * 7 + j];
    }
    const unsigned short* PpA = R + (size_t)sA * 512 + lhi * 8;
    const unsigned short* QpA = R + (size_t)dA * 512 + 256 + lhi * 8;
    const unsigned short* PpB = R + (size_t)sB * 512 + lhi * 8;
    const unsigned short* QpB = R + (size_t)dB * 512 + 256 + lhi * 8;

    short8 pA[8], qA[8], pB[8], qB[8];
#pragma unroll
    for (int kb = 0; kb < 2; ++kb) {  // prime the pipeline, depth 2
      pA[kb] = *reinterpret_cast<const short8*>(PpA + kb * 32);
      qA[kb] = *reinterpret_cast<const short8*>(QpA + kb * 32);
      pB[kb] = *reinterpret_cast<const short8*>(PpB + kb * 32);
      qB[kb] = *reinterpret_cast<const short8*>(QpB + kb * 32);
    }

    f32x4 accA = {}, accB = {};
#pragma unroll
    for (int kb = 0; kb < 8; ++kb) {
      if (kb < 6) {  // rolling prefetch, static after unroll
        pA[kb + 2] = *reinterpret_cast<const short8*>(PpA + (kb + 2) * 32);
        qA[kb + 2] = *reinterpret_cast<const short8*>(QpA + (kb + 2) * 32);
        pB[kb + 2] = *reinterpret_cast<const short8*>(PpB + (kb + 2) * 32);
        qB[kb + 2] = *reinterpret_cast<const short8*>(QpB + (kb + 2) * 32);
      }
      // w1a chunk for this kb (shared by both tiles): 14 ds_read_b128
      f32x2 wv[7][4];
      const float* ws = w1a + kb * 32 + lhi * 8;
#pragma unroll
      for (int j = 0; j < 7; ++j) {
        const float4 wa = *reinterpret_cast<const float4*>(ws + j * 256);
        const float4 wb = *reinterpret_cast<const float4*>(ws + j * 256 + 4);
        wv[j][0] = {wa.x, wa.y};
        wv[j][1] = {wa.z, wa.w};
        wv[j][2] = {wb.x, wb.y};
        wv[j][3] = {wb.z, wb.w};
      }
      TILE_KB(pA[kb], qA[kb], efA, accA);
      TILE_KB(pB[kb], qB[kb], efB, accB);
    }
    // C layout: col = lane&15 (= output n), row = (lane>>4)*4 + i (= edge in tile)
    if (l15 < 4) {
#pragma unroll
      for (int i = 0; i < 4; ++i) {
        out[(size_t)(e0 + lhi * 4 + i) * 4 + l15] = accA[i] + b2l;
        out[(size_t)(e0 + 16 + lhi * 4 + i) * 4 + l15] = accB[i] + b2l;
      }
    }
  }
#undef TILE_KB
}

extern "C" void kernel_launch(void* const* d_in, const int* in_sizes, int n_in,
                              void* d_out, int out_size, void* d_ws, size_t ws_size,
                              hipStream_t stream) {
  const float* h  = (const float*)d_in[0];
  const float* ef = (const float*)d_in[1];
  const int* src  = (const int*)d_in[2];
  const int* dst  = (const int*)d_in[3];
  const float* W1 = (const float*)d_in[4];
  const float* b1 = (const float*)d_in[5];
  const float* W2 = (const float*)d_in[6];
  const float* b2 = (const float*)d_in[7];
  float* out = (float*)d_out;

  const size_t bp_bytes = (size_t)8 * 32 * 64 * 8 * 2;  // 262144
  unsigned short* Bp = (unsigned short*)d_ws;
  unsigned short* R  = (unsigned short*)((char*)d_ws + bp_bytes);

  pack_w1<<<64, 256, 0, stream>>>(W1, Bp);
  gemm_R<<<dim3((NODES + 63) / 64, 2), 256, 0, stream>>>(h, Bp, b1, R);
  edge_mlp<<<2048, 256, 0, stream>>>(R, ef, src, dst, W1, W2, b2, out);
}

// Round 5
// 236.586 us; speedup vs baseline: 1.9186x; 1.0140x over previous
//
#include <hip/hip_runtime.h>
#include <stdint.h>

#define NODES 100000
#define EDGES 1000000
#define HF 256
#define TILES2 (EDGES / 32)

// ws layout: [0, 256KB) = packed bf16 W1 B-fragments; [256KB, +102.4MB) = R.
// R[node][512] bf16: cols 0..255 = h@W1[7:263] + b1 ("P"), cols 256..511 = h@W1[263:519] ("Q").

typedef short short8 __attribute__((ext_vector_type(8)));
typedef float f32x4 __attribute__((ext_vector_type(4)));
typedef float f32x2 __attribute__((ext_vector_type(2)));
typedef int i32x4 __attribute__((ext_vector_type(4)));

__device__ __forceinline__ unsigned short f2b(float f) {
  union { float f; uint32_t u; } v; v.f = f;
  return (unsigned short)((v.u + 0x7FFFu + ((v.u >> 16) & 1u)) >> 16);  // RNE
}
__device__ __forceinline__ float asf(uint32_t u) {
  union { uint32_t u; float f; } v; v.u = u;
  return v.f;
}
__device__ __forceinline__ uint32_t cvtpk(float lo, float hi) {
  uint32_t pk;
  asm("v_cvt_pk_bf16_f32 %0, %1, %2" : "=v"(pk) : "v"(lo), "v"(hi));
  return pk;
}

// ---------------- pack W1 rows 7..518 into MFMA B-fragment order (bf16) -------------
__global__ __launch_bounds__(256) void pack_w1(const float* __restrict__ W1,
                                               unsigned short* __restrict__ Bp) {
  int idx = blockIdx.x * 256 + threadIdx.x;  // 0..16383
  int lane = idx & 63;
  int nbg  = (idx >> 6) & 31;
  int kb   = idx >> 11;
  int n    = nbg * 16 + (lane & 15);
  int k0   = kb * 32 + (lane >> 4) * 8;
  int rbase = (n < 256) ? 7 : 263;
  int col   = n & 255;
  short8 o;
#pragma unroll
  for (int j = 0; j < 8; ++j)
    o[j] = (short)f2b(W1[(size_t)(rbase + k0 + j) * HF + col]);
  *reinterpret_cast<short8*>(Bp + (size_t)idx * 8) = o;
}

// ---------------- R = h @ Wcat (+b1 on P half)  (M=100000, K=256, N=512) -------------
// One block = 64 rows x FULL 512 cols (A staged once, not twice).
__global__ __launch_bounds__(256, 1) void gemm_R(const float* __restrict__ h,
                                                 const unsigned short* __restrict__ Bp,
                                                 const float* __restrict__ b1,
                                                 unsigned short* __restrict__ R) {
  __shared__ unsigned short A[64][264];
  const int m0 = blockIdx.x * 64;
  const int t  = threadIdx.x;
  {
    const int r = t >> 2, q = t & 3;
    const int grow = m0 + r;
    const bool valid = grow < NODES;
    const float* hp = h + (size_t)grow * HF + q * 64;
#pragma unroll
    for (int cc = 0; cc < 8; ++cc) {
      float4 a, b;
      if (valid) {
        a = *reinterpret_cast<const float4*>(hp + cc * 8);
        b = *reinterpret_cast<const float4*>(hp + cc * 8 + 4);
      } else {
        a = make_float4(0.f, 0.f, 0.f, 0.f);
        b = a;
      }
      uint32_t o32[4];
      o32[0] = cvtpk(a.x, a.y);
      o32[1] = cvtpk(a.z, a.w);
      o32[2] = cvtpk(b.x, b.y);
      o32[3] = cvtpk(b.z, b.w);
      *reinterpret_cast<uint4*>(&A[r][q * 64 + cc * 8]) =
          make_uint4(o32[0], o32[1], o32[2], o32[3]);
    }
  }
  __syncthreads();

  const int wave = t >> 6, lane = t & 63;
  const int l15 = lane & 15, lhi = lane >> 4;
  const int nbg0 = wave * 8;  // 8 16-col groups per wave -> 128 cols
  f32x4 acc[4][8] = {};
#pragma unroll
  for (int kb = 0; kb < 8; ++kb) {
    short8 bfrag[8];
#pragma unroll
    for (int nb = 0; nb < 8; ++nb)
      bfrag[nb] = *reinterpret_cast<const short8*>(
          Bp + (((size_t)(kb * 32 + nbg0 + nb) * 64 + lane) * 8));
    short8 afrag[4];
#pragma unroll
    for (int mb = 0; mb < 4; ++mb)
      afrag[mb] = *reinterpret_cast<const short8*>(&A[mb * 16 + l15][kb * 32 + lhi * 8]);
#pragma unroll
    for (int mb = 0; mb < 4; ++mb)
#pragma unroll
      for (int nb = 0; nb < 8; ++nb)
        acc[mb][nb] = __builtin_amdgcn_mfma_f32_16x16x32_bf16(
            afrag[mb], bfrag[nb], acc[mb][nb], 0, 0, 0);
  }
  const int c0 = wave * 128 + l15;  // cols 0..255 = P half (gets b1), 256..511 = Q
  float b1v[8] = {};
  if (wave < 2) {
#pragma unroll
    for (int nb = 0; nb < 8; ++nb) b1v[nb] = b1[c0 + nb * 16];
  }
#pragma unroll
  for (int mb = 0; mb < 4; ++mb) {
#pragma unroll
    for (int i = 0; i < 4; ++i) {
      const int row = m0 + mb * 16 + lhi * 4 + i;
      if (row < NODES) {
        unsigned short* rp = R + (size_t)row * 512 + c0;
#pragma unroll
        for (int nb = 0; nb < 8; ++nb) rp[nb * 16] = f2b(acc[mb][nb][i] + b1v[nb]);
      }
    }
  }
}

// ---------------- per-edge MLP, 32 edges (2 MFMA tiles) per wave iteration -----------
// Gather layout: edge = lane>>2, sub = lane&3 -> 4 ADJACENT lanes cover one 64B line
// of a node row per kb (clean TA coalescing). Compute hid in gather layout, then
// ds_bpermute the packed-bf16 A-fragment into MFMA layout (edge = lane&15, kc = lane>>4).
__global__ __launch_bounds__(256) void edge_mlp(
    const unsigned short* __restrict__ R, const float* __restrict__ ef,
    const int* __restrict__ src, const int* __restrict__ dst,
    const float* __restrict__ W1, const float* __restrict__ W2,
    const float* __restrict__ b2, float* __restrict__ out) {
  __shared__ float w1a[7 * 256];
  for (int i = threadIdx.x; i < 7 * 64; i += 256)
    reinterpret_cast<float4*>(w1a)[i] = reinterpret_cast<const float4*>(W1)[i];
  __syncthreads();

  const int lane = threadIdx.x & 63;
  const int l15 = lane & 15, lhi = lane >> 4;
  const int esub = lane >> 2;  // edge within 16-edge tile (gather layout)
  const int sub  = lane & 3;   // 16B chunk within the 64B kb-block
  // MFMA-lane m pulls af from gather-lane ((m&15)<<2)|(m>>4); bpermute wants byte idx.
  const int bperm_idx = ((((lane & 15) << 2) | (lane >> 4)) << 2);

  // B fragment: W2 zero-padded to [256][16], bf16. lane holds B[kb*32+lhi*8+j][l15]
  short8 bfrag[8];
#pragma unroll
  for (int kb = 0; kb < 8; ++kb) {
    short8 b = {0, 0, 0, 0, 0, 0, 0, 0};
    if (l15 < 4) {
#pragma unroll
      for (int j = 0; j < 8; ++j)
        b[j] = (short)f2b(W2[(size_t)(kb * 32 + lhi * 8 + j) * 4 + l15]);
    }
    bfrag[kb] = b;
  }
  const float b2l = (l15 < 4) ? b2[l15] : 0.f;

  const int wid = (blockIdx.x * blockDim.x + threadIdx.x) >> 6;
  const int nw  = (gridDim.x * blockDim.x) >> 6;

// Per-tile per-kb: unpack P/Q bf16 pairs, packed-f32 ef FMA, relu, pack,
// bpermute to MFMA layout, MFMA.
#define TILE_KB(PV, QV, EFV, ACC)                                              \
  {                                                                            \
    const uint32_t* pu = reinterpret_cast<const uint32_t*>(&PV);               \
    const uint32_t* qu = reinterpret_cast<const uint32_t*>(&QV);               \
    f32x2 hd[4];                                                               \
    _Pragma("unroll") for (int w = 0; w < 4; ++w) {                            \
      f32x2 p2 = {asf(pu[w] << 16), asf(pu[w] & 0xffff0000u)};                 \
      f32x2 q2 = {asf(qu[w] << 16), asf(qu[w] & 0xffff0000u)};                 \
      hd[w] = p2 + q2;                                                         \
    }                                                                          \
    _Pragma("unroll") for (int j = 0; j < 7; ++j) {                            \
      f32x2 e2 = {EFV[j], EFV[j]};                                             \
      hd[0] = wv[j][0] * e2 + hd[0];                                           \
      hd[1] = wv[j][1] * e2 + hd[1];                                           \
      hd[2] = wv[j][2] * e2 + hd[2];                                           \
      hd[3] = wv[j][3] * e2 + hd[3];                                           \
    }                                                                          \
    union { i32x4 i; short8 s8; } afm;                                         \
    _Pragma("unroll") for (int w = 0; w < 4; ++w) {                            \
      const float lo = fmaxf(hd[w][0], 0.f);                                   \
      const float hi = fmaxf(hd[w][1], 0.f);                                   \
      afm.i[w] = __builtin_amdgcn_ds_bpermute(bperm_idx, (int)cvtpk(lo, hi));  \
    }                                                                          \
    ACC = __builtin_amdgcn_mfma_f32_16x16x32_bf16(afm.s8, bfrag[kb], ACC, 0, 0, 0); \
  }

  for (int t = wid; t < TILES2; t += nw) {
    const int e0 = t * 32;
    const int eiA = e0 + esub;   // gather-layout edge ids
    const int eiB = eiA + 16;
    const int sA = src[eiA], dA = dst[eiA];
    const int sB = src[eiB], dB = dst[eiB];
    float efA[7], efB[7];
#pragma unroll
    for (int j = 0; j < 7; ++j) {
      efA[j] = ef[(size_t)eiA * 7 + j];
      efB[j] = ef[(size_t)eiB * 7 + j];
    }
    // byte offset: s*1024 + sub*16 + kb*64 -> 4 adjacent lanes = one 64B line
    const unsigned short* PpA = R + (size_t)sA * 512 + sub * 8;
    const unsigned short* QpA = R + (size_t)dA * 512 + 256 + sub * 8;
    const unsigned short* PpB = R + (size_t)sB * 512 + sub * 8;
    const unsigned short* QpB = R + (size_t)dB * 512 + 256 + sub * 8;

    short8 pA[8], qA[8], pB[8], qB[8];
#pragma unroll
    for (int kb = 0; kb < 2; ++kb) {  // prime the pipeline, depth 2
      pA[kb] = *reinterpret_cast<const short8*>(PpA + kb * 32);
      qA[kb] = *reinterpret_cast<const short8*>(QpA + kb * 32);
      pB[kb] = *reinterpret_cast<const short8*>(PpB + kb * 32);
      qB[kb] = *reinterpret_cast<const short8*>(QpB + kb * 32);
    }

    f32x4 accA = {}, accB = {};
#pragma unroll
    for (int kb = 0; kb < 8; ++kb) {
      if (kb < 6) {  // rolling prefetch, static after unroll
        pA[kb + 2] = *reinterpret_cast<const short8*>(PpA + (kb + 2) * 32);
        qA[kb + 2] = *reinterpret_cast<const short8*>(QpA + (kb + 2) * 32);
        pB[kb + 2] = *reinterpret_cast<const short8*>(PpB + (kb + 2) * 32);
        qB[kb + 2] = *reinterpret_cast<const short8*>(QpB + (kb + 2) * 32);
      }
      // w1a chunk for this kb (k-window now indexed by sub): 14 ds_read_b128
      f32x2 wv[7][4];
      const float* ws = w1a + kb * 32 + sub * 8;
#pragma unroll
      for (int j = 0; j < 7; ++j) {
        const float4 wa = *reinterpret_cast<const float4*>(ws + j * 256);
        const float4 wb = *reinterpret_cast<const float4*>(ws + j * 256 + 4);
        wv[j][0] = {wa.x, wa.y};
        wv[j][1] = {wa.z, wa.w};
        wv[j][2] = {wb.x, wb.y};
        wv[j][3] = {wb.z, wb.w};
      }
      TILE_KB(pA[kb], qA[kb], efA, accA);
      TILE_KB(pB[kb], qB[kb], efB, accB);
    }
    // C layout: col = lane&15 (= output n), row = (lane>>4)*4 + i (= edge in tile)
    if (l15 < 4) {
#pragma unroll
      for (int i = 0; i < 4; ++i) {
        out[(size_t)(e0 + lhi * 4 + i) * 4 + l15] = accA[i] + b2l;
        out[(size_t)(e0 + 16 + lhi * 4 + i) * 4 + l15] = accB[i] + b2l;
      }
    }
  }
#undef TILE_KB
}

extern "C" void kernel_launch(void* const* d_in, const int* in_sizes, int n_in,
                              void* d_out, int out_size, void* d_ws, size_t ws_size,
                              hipStream_t stream) {
  const float* h  = (const float*)d_in[0];
  const float* ef = (const float*)d_in[1];
  const int* src  = (const int*)d_in[2];
  const int* dst  = (const int*)d_in[3];
  const float* W1 = (const float*)d_in[4];
  const float* b1 = (const float*)d_in[5];
  const float* W2 = (const float*)d_in[6];
  const float* b2 = (const float*)d_in[7];
  float* out = (float*)d_out;

  const size_t bp_bytes = (size_t)8 * 32 * 64 * 8 * 2;  // 262144
  unsigned short* Bp = (unsigned short*)d_ws;
  unsigned short* R  = (unsigned short*)((char*)d_ws + bp_bytes);

  pack_w1<<<64, 256, 0, stream>>>(W1, Bp);
  gemm_R<<<(NODES + 63) / 64, 256, 0, stream>>>(h, Bp, b1, R);
  edge_mlp<<<2048, 256, 0, stream>>>(R, ef, src, dst, W1, W2, b2, out);
}